// Round 2
// baseline (186.117 us; speedup 1.0000x reference)
//
#include <hip/hip_runtime.h>
#include <hip/hip_bf16.h>

typedef __bf16 bf16_t;
typedef __bf16 bf16x8 __attribute__((ext_vector_type(8)));
typedef float f32x4 __attribute__((ext_vector_type(4)));

// ---------------------------------------------------------------------------
// fused fp32 -> bf16 conversion for all three inputs (one dispatch).
// chunk counts: input 8192*768/8 = 786432, fc_w 256*768/8 = 24576,
//               bi_w 3072*256/8 = 98304  -> total 909312 chunks
// ---------------------------------------------------------------------------
__global__ __launch_bounds__(256)
void cvt_all(const float* __restrict__ in, bf16_t* __restrict__ o_in,
             const float* __restrict__ fw, bf16_t* __restrict__ o_fw,
             const float* __restrict__ bw, bf16_t* __restrict__ o_bw) {
    int i = blockIdx.x * 256 + threadIdx.x;
    const float* s;
    bf16_t* d;
    int k;
    if (i < 786432)      { s = in; d = o_in; k = i; }
    else if (i < 811008) { s = fw; d = o_fw; k = i - 786432; }
    else if (i < 909312) { s = bw; d = o_bw; k = i - 811008; }
    else return;
    float4 a = ((const float4*)s)[k * 2];
    float4 b = ((const float4*)s)[k * 2 + 1];
    bf16x8 v;
    v[0] = (bf16_t)a.x; v[1] = (bf16_t)a.y; v[2] = (bf16_t)a.z; v[3] = (bf16_t)a.w;
    v[4] = (bf16_t)b.x; v[5] = (bf16_t)b.y; v[6] = (bf16_t)b.z; v[7] = (bf16_t)b.w;
    ((bf16x8*)d)[k] = v;
}

// ---------------------------------------------------------------------------
// gemm_bt: C[M,N] = A[M,K] * B[N,K]^T  (row-major, K contiguous), BK=64.
// Tile BM x BN, 4 waves in 2x2; each wave owns (BM/2)x(BN/2); MR=BM/32,
// NR=BN/32 16x16 fragments per wave.
//
// Wide-store remap: MFMA fragment n loads B rows (wcol + lrow*NR + n), so
// each lane's NR accumulators are NR CONSECUTIVE output columns
// (col = cb0 + n, cb0 = nblk*BN + wcol + lrow*NR) -> vectorized epilogue
// stores (float4 / packed bf16) instead of scalar scatter.
//
// EPI: 0 = fp32 out, batched (sA/sB/sC), no bias
//      1 = bf16 out + bias[col]
//      2 = bf16 out + bias[col & 255]
// Shapes guarantee M%BM == N%BN == K%64 == 0.
// ---------------------------------------------------------------------------
template <int BM, int BN, int EPI>
__global__ __launch_bounds__(256)
void gemm_bt(const bf16_t* __restrict__ A, const bf16_t* __restrict__ Bm,
             void* __restrict__ Cv, const float* __restrict__ bias,
             int M, int N, int K, long sA, long sB, long sC) {
    constexpr int MR = BM / 32;
    constexpr int NR = BN / 32;
    typedef float fvec __attribute__((ext_vector_type(NR)));
    typedef bf16_t bvec __attribute__((ext_vector_type(NR)));

    __shared__ bf16_t As[BM * 64];
    __shared__ bf16_t Bs[BN * 64];

    const int tid  = threadIdx.x;
    const int lane = tid & 63;
    const int wave = tid >> 6;
    const int mblk = blockIdx.x, nblk = blockIdx.y, bz = blockIdx.z;

    const bf16_t* Ab = A + (long)bz * sA + (long)mblk * BM * K;
    const bf16_t* Bb = Bm + (long)bz * sB + (long)nblk * BN * K;

    f32x4 acc[MR][NR] = {};

    const int wrow = (wave >> 1) * (BM / 2);
    const int wcol = (wave & 1) * (BN / 2);
    const int lrow = lane & 15;
    const int kgrp = lane >> 4;

    for (int k0 = 0; k0 < K; k0 += 64) {
#pragma unroll
        for (int it = 0; it < MR; ++it) {
            const int chunk = it * 256 + tid;
            const int row = chunk >> 3, c8 = chunk & 7;
            __builtin_amdgcn_global_load_lds(
                (const __attribute__((address_space(1))) void*)(Ab + (long)row * K + k0 + c8 * 8),
                (__attribute__((address_space(3))) void*)(As + chunk * 8), 16, 0, 0);
        }
#pragma unroll
        for (int it = 0; it < NR; ++it) {
            const int chunk = it * 256 + tid;
            const int row = chunk >> 3, c8 = chunk & 7;
            __builtin_amdgcn_global_load_lds(
                (const __attribute__((address_space(1))) void*)(Bb + (long)row * K + k0 + c8 * 8),
                (__attribute__((address_space(3))) void*)(Bs + chunk * 8), 16, 0, 0);
        }
        __syncthreads();

#pragma unroll
        for (int kk = 0; kk < 64; kk += 32) {
            const int koff = kk + kgrp * 8;
            bf16x8 af[MR], bfr[NR];
#pragma unroll
            for (int m = 0; m < MR; ++m)
                af[m] = *(const bf16x8*)(As + (wrow + m * 16 + lrow) * 64 + koff);
#pragma unroll
            for (int n = 0; n < NR; ++n)
                bfr[n] = *(const bf16x8*)(Bs + (wcol + lrow * NR + n) * 64 + koff);
#pragma unroll
            for (int m = 0; m < MR; ++m)
#pragma unroll
                for (int n = 0; n < NR; ++n)
                    acc[m][n] = __builtin_amdgcn_mfma_f32_16x16x32_bf16(af[m], bfr[n], acc[m][n], 0, 0, 0);
        }
        __syncthreads();
    }

    // lane's outputs: rows rbase + m*16 + j, cols cb0 + n (n consecutive!)
    const long rbase = (long)mblk * BM + wrow + kgrp * 4;
    const long cb0   = (long)nblk * BN + wcol + lrow * NR;
    if constexpr (EPI == 0) {
        float* C = (float*)Cv + (long)bz * sC;
#pragma unroll
        for (int m = 0; m < MR; ++m)
#pragma unroll
            for (int j = 0; j < 4; ++j) {
                fvec v;
#pragma unroll
                for (int n = 0; n < NR; ++n) v[n] = acc[m][n][j];
                *(fvec*)(C + (rbase + m * 16 + j) * N + cb0) = v;
            }
    } else {
        bf16_t* C = (bf16_t*)Cv;
        const float* bp = (EPI == 1) ? (bias + cb0) : (bias + (cb0 & 255));
        fvec bv = *(const fvec*)bp;
#pragma unroll
        for (int m = 0; m < MR; ++m)
#pragma unroll
            for (int j = 0; j < 4; ++j) {
                bvec v;
#pragma unroll
                for (int n = 0; n < NR; ++n) v[n] = (bf16_t)(acc[m][n][j] + bv[n]);
                *(bvec*)(C + (rbase + m * 16 + j) * N + cb0) = v;
            }
    }
}

// ---------------------------------------------------------------------------
// B=8, S=1024, IN=768, E=256, L=12
//   t  = input[8192,768] @ fc_w[256,768]^T + fc_b          -> bf16 [8192,256]
//   bl = t[8192,256] @ bi_w[3072,256]^T + bias[col&255]    -> bf16 [8192,3072]
//   out_b = bl_b[12288,256] @ t_b[1024,256]^T              -> f32, batched x8
// ---------------------------------------------------------------------------
extern "C" void kernel_launch(void* const* d_in, const int* in_sizes, int n_in,
                              void* d_out, int out_size, void* d_ws, size_t ws_size,
                              hipStream_t stream) {
    const float* input = (const float*)d_in[0];
    const float* fc_w  = (const float*)d_in[1];
    const float* fc_b  = (const float*)d_in[2];
    const float* bi_w  = (const float*)d_in[3];
    const float* bias  = (const float*)d_in[4];

    char* ws = (char*)d_ws;
    bf16_t* inA = (bf16_t*)(ws);             // 8192*768*2  = 12,582,912
    bf16_t* wfc = (bf16_t*)(ws + 12582912);  // 256*768*2   =    393,216
    bf16_t* wbi = (bf16_t*)(ws + 12976128);  // 3072*256*2  =  1,572,864
    bf16_t* t   = (bf16_t*)(ws + 14548992);  // 8192*256*2  =  4,194,304
    bf16_t* bl  = (bf16_t*)(ws + 18743296);  // 8192*3072*2 = 50,331,648

    cvt_all<<<dim3(3552), dim3(256), 0, stream>>>(input, inA, fc_w, wfc, bi_w, wbi);

    // GEMM1: t = inA @ wfc^T + fc_b   (64x64 tile -> 512 blocks, 2/CU)
    gemm_bt<64, 64, 1><<<dim3(128, 4, 1), dim3(256), 0, stream>>>(
        inA, wfc, (void*)t, fc_b, 8192, 256, 768, 0L, 0L, 0L);

    // GEMM2: bl = t @ wbi^T + bias[col&255]
    gemm_bt<128, 128, 2><<<dim3(64, 24, 1), dim3(256), 0, stream>>>(
        t, wbi, (void*)bl, bias, 8192, 3072, 256, 0L, 0L, 0L);

    // GEMM3 (batched over 8): out_b = bl_b @ t_b^T
    gemm_bt<128, 128, 0><<<dim3(96, 8, 8), dim3(256), 0, stream>>>(
        bl, t, d_out, nullptr, 12288, 1024, 256,
        (long)12288 * 256, (long)1024 * 256, (long)12288 * 1024);
}

// Round 3
// 148.263 us; speedup vs baseline: 1.2553x; 1.2553x over previous
//
#include <hip/hip_runtime.h>
#include <hip/hip_bf16.h>

typedef __bf16 bf16_t;
typedef __bf16 bf16x8 __attribute__((ext_vector_type(8)));
typedef __bf16 bf16x4 __attribute__((ext_vector_type(4)));
typedef float f32x4 __attribute__((ext_vector_type(4)));

// ---------------------------------------------------------------------------
// fused fp32 -> bf16 conversion for all three inputs (one dispatch).
// ---------------------------------------------------------------------------
__global__ __launch_bounds__(256)
void cvt_all(const float* __restrict__ in, bf16_t* __restrict__ o_in,
             const float* __restrict__ fw, bf16_t* __restrict__ o_fw,
             const float* __restrict__ bw, bf16_t* __restrict__ o_bw) {
    int i = blockIdx.x * 256 + threadIdx.x;
    const float* s;
    bf16_t* d;
    int k;
    if (i < 786432)      { s = in; d = o_in; k = i; }
    else if (i < 811008) { s = fw; d = o_fw; k = i - 786432; }
    else if (i < 909312) { s = bw; d = o_bw; k = i - 811008; }
    else return;
    float4 a = ((const float4*)s)[k * 2];
    float4 b = ((const float4*)s)[k * 2 + 1];
    bf16x8 v;
    v[0] = (bf16_t)a.x; v[1] = (bf16_t)a.y; v[2] = (bf16_t)a.z; v[3] = (bf16_t)a.w;
    v[4] = (bf16_t)b.x; v[5] = (bf16_t)b.y; v[6] = (bf16_t)b.z; v[7] = (bf16_t)b.w;
    ((bf16x8*)d)[k] = v;
}

// ---------------------------------------------------------------------------
// gemm_bt 64x64 (m97 structure) — used for GEMM1 only (K=768, N=256 small).
// Wide-store remap: B-frag n from LDS row (wcol + lrow*NR + n).
// ---------------------------------------------------------------------------
template <int BM, int BN, int EPI>
__global__ __launch_bounds__(256)
void gemm_bt(const bf16_t* __restrict__ A, const bf16_t* __restrict__ Bm,
             void* __restrict__ Cv, const float* __restrict__ bias,
             int M, int N, int K) {
    constexpr int MR = BM / 32;
    constexpr int NR = BN / 32;
    typedef float fvec __attribute__((ext_vector_type(NR)));
    typedef bf16_t bvec __attribute__((ext_vector_type(NR)));

    __shared__ bf16_t As[BM * 64];
    __shared__ bf16_t Bs[BN * 64];

    const int tid  = threadIdx.x;
    const int lane = tid & 63;
    const int wave = tid >> 6;
    const int mblk = blockIdx.x, nblk = blockIdx.y;

    const bf16_t* Ab = A + (long)mblk * BM * K;
    const bf16_t* Bb = Bm + (long)nblk * BN * K;

    f32x4 acc[MR][NR] = {};

    const int wrow = (wave >> 1) * (BM / 2);
    const int wcol = (wave & 1) * (BN / 2);
    const int lrow = lane & 15;
    const int kgrp = lane >> 4;

    for (int k0 = 0; k0 < K; k0 += 64) {
#pragma unroll
        for (int it = 0; it < MR; ++it) {
            const int chunk = it * 256 + tid;
            const int row = chunk >> 3, c8 = chunk & 7;
            __builtin_amdgcn_global_load_lds(
                (const __attribute__((address_space(1))) void*)(Ab + (long)row * K + k0 + c8 * 8),
                (__attribute__((address_space(3))) void*)(As + chunk * 8), 16, 0, 0);
        }
#pragma unroll
        for (int it = 0; it < NR; ++it) {
            const int chunk = it * 256 + tid;
            const int row = chunk >> 3, c8 = chunk & 7;
            __builtin_amdgcn_global_load_lds(
                (const __attribute__((address_space(1))) void*)(Bb + (long)row * K + k0 + c8 * 8),
                (__attribute__((address_space(3))) void*)(Bs + chunk * 8), 16, 0, 0);
        }
        __syncthreads();

#pragma unroll
        for (int kk = 0; kk < 64; kk += 32) {
            const int koff = kk + kgrp * 8;
            bf16x8 af[MR], bfr[NR];
#pragma unroll
            for (int m = 0; m < MR; ++m)
                af[m] = *(const bf16x8*)(As + (wrow + m * 16 + lrow) * 64 + koff);
#pragma unroll
            for (int n = 0; n < NR; ++n)
                bfr[n] = *(const bf16x8*)(Bs + (wcol + lrow * NR + n) * 64 + koff);
#pragma unroll
            for (int m = 0; m < MR; ++m)
#pragma unroll
                for (int n = 0; n < NR; ++n)
                    acc[m][n] = __builtin_amdgcn_mfma_f32_16x16x32_bf16(af[m], bfr[n], acc[m][n], 0, 0, 0);
        }
        __syncthreads();
    }

    const long rbase = (long)mblk * BM + wrow + kgrp * 4;
    const long cb0   = (long)nblk * BN + wcol + lrow * NR;
    bf16_t* C = (bf16_t*)Cv;
    const float* bp = bias + cb0;
    fvec bv = *(const fvec*)bp;
#pragma unroll
    for (int m = 0; m < MR; ++m)
#pragma unroll
        for (int j = 0; j < 4; ++j) {
            bvec v;
#pragma unroll
            for (int n = 0; n < NR; ++n) v[n] = (bf16_t)(acc[m][n][j] + bv[n]);
            *(bvec*)(C + (rbase + m * 16 + j) * N + cb0) = v;
        }
}

// ---------------------------------------------------------------------------
// 8-phase 256x256 GEMM, K=256 fixed (4 K-tiles, 2 unrolled iterations).
// C[M,256k..] = A[Mx256] * B[Nx256]^T, both row-major K-contiguous bf16.
// 512 threads = 8 waves (2M x 4N); per-wave output 128x64.
// LDS 128 KiB dynamic: A: (buf*2+half)*8192 ; B: 32768 + (buf*2+half)*8192.
// T2 swizzle both-sides: A key (row&7), B key ((row>>2)&7) (wide-store remap
// reads B rows at stride 4). T4 counted vmcnt(4). T5 setprio around MFMA.
// EPI 0: fp32 out, batched; EPI 2: bf16 out + bias[col&255].
// XCD=1: bz = bid&7 (one batch per XCD), 4 consecutive blocks share A-panel.
// ---------------------------------------------------------------------------
template <int EPI, int XCD, int NMB, int NNB>
__global__ __launch_bounds__(512, 2)
void gemm8p(const bf16_t* __restrict__ A, const bf16_t* __restrict__ Bm,
            void* __restrict__ Cv, const float* __restrict__ bias,
            int N, long sA, long sB, long sC) {
    constexpr int K = 256;
    extern __shared__ bf16_t lds[];

    const int tid  = threadIdx.x;
    const int lane = tid & 63;
    const int wave = tid >> 6;
    const int wm = wave >> 2, wn = wave & 3;
    const int lrow = lane & 15, kgrp = lane >> 4;

    int mblk, nblk, bz;
    {
        int L = blockIdx.x;
        if (XCD) { bz = L & 7; int w = L >> 3; nblk = w % NNB; mblk = w / NNB; }
        else     { bz = 0;     mblk = L % NMB; nblk = L / NMB; }
    }

    const bf16_t* Ab = A + (long)bz * sA + (long)mblk * 256 * K;
    const bf16_t* Bb = Bm + (long)bz * sB + (long)nblk * 256 * K;

    // staging precompute: thread covers chunks c0=tid, c1=512+tid of each half
    const int c0 = tid, c1 = 512 + tid;
    const int r0 = c0 >> 3, r1 = c1 >> 3;
    const int ca0 = (c0 & 7) ^ (r0 & 7),        ca1 = (c1 & 7) ^ (r1 & 7);
    const int cb0 = (c0 & 7) ^ ((r0 >> 2) & 7), cb1 = (c1 & 7) ^ ((r1 >> 2) & 7);

    auto stageA = [&](int t, int h) {
        const bf16_t* s0 = Ab + (long)(h * 128 + r0) * K + t * 64 + ca0 * 8;
        const bf16_t* s1 = Ab + (long)(h * 128 + r1) * K + t * 64 + ca1 * 8;
        bf16_t* d = lds + ((t & 1) * 2 + h) * 8192;
        __builtin_amdgcn_global_load_lds((const __attribute__((address_space(1))) void*)s0,
            (__attribute__((address_space(3))) void*)(d + c0 * 8), 16, 0, 0);
        __builtin_amdgcn_global_load_lds((const __attribute__((address_space(1))) void*)s1,
            (__attribute__((address_space(3))) void*)(d + c1 * 8), 16, 0, 0);
    };
    auto stageB = [&](int t, int h) {
        const bf16_t* s0 = Bb + (long)(h * 128 + r0) * K + t * 64 + cb0 * 8;
        const bf16_t* s1 = Bb + (long)(h * 128 + r1) * K + t * 64 + cb1 * 8;
        bf16_t* d = lds + 32768 + ((t & 1) * 2 + h) * 8192;
        __builtin_amdgcn_global_load_lds((const __attribute__((address_space(1))) void*)s0,
            (__attribute__((address_space(3))) void*)(d + c0 * 8), 16, 0, 0);
        __builtin_amdgcn_global_load_lds((const __attribute__((address_space(1))) void*)s1,
            (__attribute__((address_space(3))) void*)(d + c1 * 8), 16, 0, 0);
    };
    auto ldA = [&](int t, int mf, int kk) -> bf16x8 {
        const int row = mf * 16 + lrow;
        const int col = (kk * 32 + kgrp * 8) ^ ((row & 7) << 3);
        return *(const bf16x8*)(lds + ((t & 1) * 2 + wm) * 8192 + row * 64 + col);
    };
    auto ldB = [&](int t, int g, int kk) -> bf16x8 {
        const int row = (wn & 1) * 64 + lrow * 4 + g;
        const int col = (kk * 32 + kgrp * 8) ^ (((row >> 2) & 7) << 3);
        return *(const bf16x8*)(lds + 32768 + ((t & 1) * 2 + (wn >> 1)) * 8192 + row * 64 + col);
    };

    f32x4 acc[8][4] = {};
    bf16x8 bfr[4][2];

    // prologue: T0 A+B, T1 B; wait until only T1B (4 loads) in flight
    stageA(0, 0); stageA(0, 1); stageB(0, 0); stageB(0, 1); stageB(1, 0); stageB(1, 1);
    asm volatile("s_waitcnt vmcnt(4)" ::: "memory");
    __builtin_amdgcn_s_barrier();

#pragma unroll
    for (int i = 0; i < 2; ++i) {
#pragma unroll
        for (int p = 0; p < 8; ++p) {
            const int q = p & 3;
            const int t = 2 * i + (p >> 2);
            bf16x8 af[2][2];
            if (q == 0) {
#pragma unroll
                for (int g = 0; g < 4; ++g) { bfr[g][0] = ldB(t, g, 0); bfr[g][1] = ldB(t, g, 1); }
            }
#pragma unroll
            for (int mm = 0; mm < 2; ++mm) { af[mm][0] = ldA(t, 2 * q + mm, 0); af[mm][1] = ldA(t, 2 * q + mm, 1); }

            // stage schedule: p0,p1: T(2i+1)A; p2,p3: T(2i+2)B; p4,p5: T(2i+2)A; p6,p7: T(2i+3)B
            if (p == 0) stageA(2 * i + 1, 0);
            else if (p == 1) stageA(2 * i + 1, 1);
            else if (p == 2) { if (2 * i + 2 < 4) stageB(2 * i + 2, 0); }
            else if (p == 3) { if (2 * i + 2 < 4) stageB(2 * i + 2, 1); }
            else if (p == 4) { if (2 * i + 2 < 4) stageA(2 * i + 2, 0); }
            else if (p == 5) { if (2 * i + 2 < 4) stageA(2 * i + 2, 1); }
            else if (p == 6) { if (2 * i + 3 < 4) stageB(2 * i + 3, 0); }
            else             { if (2 * i + 3 < 4) stageB(2 * i + 3, 1); }

            __builtin_amdgcn_s_barrier();
            asm volatile("s_waitcnt lgkmcnt(0)" ::: "memory");
            __builtin_amdgcn_s_setprio(1);
#pragma unroll
            for (int mm = 0; mm < 2; ++mm)
#pragma unroll
                for (int g = 0; g < 4; ++g)
#pragma unroll
                    for (int kk = 0; kk < 2; ++kk)
                        acc[2 * q + mm][g] = __builtin_amdgcn_mfma_f32_16x16x32_bf16(
                            af[mm][kk], bfr[g][kk], acc[2 * q + mm][g], 0, 0, 0);
            __builtin_amdgcn_s_setprio(0);

            if (p == 3) {
                if (2 * i + 2 < 4) asm volatile("s_waitcnt vmcnt(4)" ::: "memory");
                else               asm volatile("s_waitcnt vmcnt(0)" ::: "memory");
            } else if (p == 7) {
                if (2 * i + 2 < 4) asm volatile("s_waitcnt vmcnt(4)" ::: "memory");
            }
            __builtin_amdgcn_s_barrier();
        }
    }

    // epilogue: lane owns rows (rb + m*16 + j), 4 consecutive cols at cb
    const long rb = (long)mblk * 256 + wm * 128 + kgrp * 4;
    const long cb = (long)nblk * 256 + wn * 64 + lrow * 4;
    if constexpr (EPI == 0) {
        float* C = (float*)Cv + (long)bz * sC;
#pragma unroll
        for (int m = 0; m < 8; ++m)
#pragma unroll
            for (int j = 0; j < 4; ++j) {
                f32x4 v = { acc[m][0][j], acc[m][1][j], acc[m][2][j], acc[m][3][j] };
                *(f32x4*)(C + (rb + m * 16 + j) * N + cb) = v;
            }
    } else {
        bf16_t* C = (bf16_t*)Cv;
        f32x4 bv = *(const f32x4*)(bias + (int)(cb & 255));
#pragma unroll
        for (int m = 0; m < 8; ++m)
#pragma unroll
            for (int j = 0; j < 4; ++j) {
                bf16x4 v;
#pragma unroll
                for (int g = 0; g < 4; ++g) v[g] = (bf16_t)(acc[m][g][j] + bv[g]);
                *(bf16x4*)(C + (rb + m * 16 + j) * N + cb) = v;
            }
    }
}

// ---------------------------------------------------------------------------
// B=8, S=1024, IN=768, E=256, L=12
// ---------------------------------------------------------------------------
extern "C" void kernel_launch(void* const* d_in, const int* in_sizes, int n_in,
                              void* d_out, int out_size, void* d_ws, size_t ws_size,
                              hipStream_t stream) {
    const float* input = (const float*)d_in[0];
    const float* fc_w  = (const float*)d_in[1];
    const float* fc_b  = (const float*)d_in[2];
    const float* bi_w  = (const float*)d_in[3];
    const float* bias  = (const float*)d_in[4];

    char* ws = (char*)d_ws;
    bf16_t* inA = (bf16_t*)(ws);             // 8192*768*2
    bf16_t* wfc = (bf16_t*)(ws + 12582912);  // 256*768*2
    bf16_t* wbi = (bf16_t*)(ws + 12976128);  // 3072*256*2
    bf16_t* t   = (bf16_t*)(ws + 14548992);  // 8192*256*2
    bf16_t* bl  = (bf16_t*)(ws + 18743296);  // 8192*3072*2

    cvt_all<<<dim3(3552), dim3(256), 0, stream>>>(input, inA, fc_w, wfc, bi_w, wbi);

    // GEMM1: t = inA @ wfc^T + fc_b   (K=768; 64x64 tile -> 512 blocks)
    gemm_bt<64, 64, 1><<<dim3(128, 4), dim3(256), 0, stream>>>(
        inA, wfc, (void*)t, fc_b, 8192, 256, 768);

    // GEMM2: bl = t @ wbi^T + bias[col&255]  (8-phase 256^2; 32x12 = 384 blocks)
    gemm8p<2, 0, 32, 12><<<dim3(384), dim3(512), 131072, stream>>>(
        t, wbi, (void*)bl, bias, 3072, 0L, 0L, 0L);

    // GEMM3 (batched x8): out_b = bl_b @ t_b^T  (8-phase; 48x4x8 = 1536 blocks)
    gemm8p<0, 1, 48, 4><<<dim3(1536), dim3(512), 131072, stream>>>(
        bl, t, d_out, nullptr, 1024,
        (long)12288 * 256, (long)1024 * 256, (long)12288 * 1024);
}

// Round 4
// 135.918 us; speedup vs baseline: 1.3693x; 1.0908x over previous
//
#include <hip/hip_runtime.h>
#include <hip/hip_bf16.h>

typedef __bf16 bf16_t;
typedef __bf16 bf16x8 __attribute__((ext_vector_type(8)));
typedef __bf16 bf16x4 __attribute__((ext_vector_type(4)));
typedef float f32x4 __attribute__((ext_vector_type(4)));

// ---------------------------------------------------------------------------
// fused fp32 -> bf16 conversion for all three inputs (one dispatch).
// ---------------------------------------------------------------------------
__global__ __launch_bounds__(256)
void cvt_all(const float* __restrict__ in, bf16_t* __restrict__ o_in,
             const float* __restrict__ fw, bf16_t* __restrict__ o_fw,
             const float* __restrict__ bw, bf16_t* __restrict__ o_bw) {
    int i = blockIdx.x * 256 + threadIdx.x;
    const float* s;
    bf16_t* d;
    int k;
    if (i < 786432)      { s = in; d = o_in; k = i; }
    else if (i < 811008) { s = fw; d = o_fw; k = i - 786432; }
    else if (i < 909312) { s = bw; d = o_bw; k = i - 811008; }
    else return;
    float4 a = ((const float4*)s)[k * 2];
    float4 b = ((const float4*)s)[k * 2 + 1];
    bf16x8 v;
    v[0] = (bf16_t)a.x; v[1] = (bf16_t)a.y; v[2] = (bf16_t)a.z; v[3] = (bf16_t)a.w;
    v[4] = (bf16_t)b.x; v[5] = (bf16_t)b.y; v[6] = (bf16_t)b.z; v[7] = (bf16_t)b.w;
    ((bf16x8*)d)[k] = v;
}

// ---------------------------------------------------------------------------
// gemm_bt 64x64 (m97 structure) — used for GEMM1 only (K=768, N=256 small).
// Wide-store remap: B-frag n from LDS row (wcol + lrow*NR + n).
// ---------------------------------------------------------------------------
template <int BM, int BN, int EPI>
__global__ __launch_bounds__(256)
void gemm_bt(const bf16_t* __restrict__ A, const bf16_t* __restrict__ Bm,
             void* __restrict__ Cv, const float* __restrict__ bias,
             int M, int N, int K) {
    constexpr int MR = BM / 32;
    constexpr int NR = BN / 32;
    typedef float fvec __attribute__((ext_vector_type(NR)));
    typedef bf16_t bvec __attribute__((ext_vector_type(NR)));

    __shared__ bf16_t As[BM * 64];
    __shared__ bf16_t Bs[BN * 64];

    const int tid  = threadIdx.x;
    const int lane = tid & 63;
    const int wave = tid >> 6;
    const int mblk = blockIdx.x, nblk = blockIdx.y;

    const bf16_t* Ab = A + (long)mblk * BM * K;
    const bf16_t* Bb = Bm + (long)nblk * BN * K;

    f32x4 acc[MR][NR] = {};

    const int wrow = (wave >> 1) * (BM / 2);
    const int wcol = (wave & 1) * (BN / 2);
    const int lrow = lane & 15;
    const int kgrp = lane >> 4;

    for (int k0 = 0; k0 < K; k0 += 64) {
#pragma unroll
        for (int it = 0; it < MR; ++it) {
            const int chunk = it * 256 + tid;
            const int row = chunk >> 3, c8 = chunk & 7;
            __builtin_amdgcn_global_load_lds(
                (const __attribute__((address_space(1))) void*)(Ab + (long)row * K + k0 + c8 * 8),
                (__attribute__((address_space(3))) void*)(As + chunk * 8), 16, 0, 0);
        }
#pragma unroll
        for (int it = 0; it < NR; ++it) {
            const int chunk = it * 256 + tid;
            const int row = chunk >> 3, c8 = chunk & 7;
            __builtin_amdgcn_global_load_lds(
                (const __attribute__((address_space(1))) void*)(Bb + (long)row * K + k0 + c8 * 8),
                (__attribute__((address_space(3))) void*)(Bs + chunk * 8), 16, 0, 0);
        }
        __syncthreads();

#pragma unroll
        for (int kk = 0; kk < 64; kk += 32) {
            const int koff = kk + kgrp * 8;
            bf16x8 af[MR], bfr[NR];
#pragma unroll
            for (int m = 0; m < MR; ++m)
                af[m] = *(const bf16x8*)(As + (wrow + m * 16 + lrow) * 64 + koff);
#pragma unroll
            for (int n = 0; n < NR; ++n)
                bfr[n] = *(const bf16x8*)(Bs + (wcol + lrow * NR + n) * 64 + koff);
#pragma unroll
            for (int m = 0; m < MR; ++m)
#pragma unroll
                for (int n = 0; n < NR; ++n)
                    acc[m][n] = __builtin_amdgcn_mfma_f32_16x16x32_bf16(af[m], bfr[n], acc[m][n], 0, 0, 0);
        }
        __syncthreads();
    }

    const long rbase = (long)mblk * BM + wrow + kgrp * 4;
    const long cb0   = (long)nblk * BN + wcol + lrow * NR;
    bf16_t* C = (bf16_t*)Cv;
    const float* bp = bias + cb0;
    fvec bv = *(const fvec*)bp;
#pragma unroll
    for (int m = 0; m < MR; ++m)
#pragma unroll
        for (int j = 0; j < 4; ++j) {
            bvec v;
#pragma unroll
            for (int n = 0; n < NR; ++n) v[n] = (bf16_t)(acc[m][n][j] + bv[n]);
            *(bvec*)(C + (rbase + m * 16 + j) * N + cb0) = v;
        }
}

// ---------------------------------------------------------------------------
// 8-phase 256x256 GEMM, K=256 fixed (4 K-tiles, 2 unrolled iterations).
// C[M,256k..] = A[Mx256] * B[Nx256]^T, both row-major K-contiguous bf16.
// 512 threads = 8 waves (2M x 4N); per-wave output 128x64.
// LDS 128 KiB dynamic: A: (buf*2+half)*8192 ; B: 32768 + (buf*2+half)*8192.
// T2 swizzle both-sides: A key (row&7), B key ((row>>2)&7). T4 counted
// vmcnt(4). T5 setprio around MFMA.
// EPI 0: fp32 out (NON-TEMPORAL stores — out is never re-read; keeps the
//        8x4MB L2s free for the concurrent bl read stream), batched.
// EPI 2: bf16 out + bias[col&255], cached stores (bl IS re-read by GEMM3).
// XCD=1: bz = bid&7 (one batch per XCD).
// ---------------------------------------------------------------------------
template <int EPI, int XCD, int NMB, int NNB>
__global__ __launch_bounds__(512, 2)
void gemm8p(const bf16_t* __restrict__ A, const bf16_t* __restrict__ Bm,
            void* __restrict__ Cv, const float* __restrict__ bias,
            int N, long sA, long sB, long sC) {
    constexpr int K = 256;
    extern __shared__ bf16_t lds[];

    const int tid  = threadIdx.x;
    const int lane = tid & 63;
    const int wave = tid >> 6;
    const int wm = wave >> 2, wn = wave & 3;
    const int lrow = lane & 15, kgrp = lane >> 4;

    int mblk, nblk, bz;
    {
        int L = blockIdx.x;
        if (XCD) { bz = L & 7; int w = L >> 3; nblk = w % NNB; mblk = w / NNB; }
        else     { bz = 0;     mblk = L % NMB; nblk = L / NMB; }
    }

    const bf16_t* Ab = A + (long)bz * sA + (long)mblk * 256 * K;
    const bf16_t* Bb = Bm + (long)bz * sB + (long)nblk * 256 * K;

    // staging precompute: thread covers chunks c0=tid, c1=512+tid of each half
    const int c0 = tid, c1 = 512 + tid;
    const int r0 = c0 >> 3, r1 = c1 >> 3;
    const int ca0 = (c0 & 7) ^ (r0 & 7),        ca1 = (c1 & 7) ^ (r1 & 7);
    const int cb0 = (c0 & 7) ^ ((r0 >> 2) & 7), cb1 = (c1 & 7) ^ ((r1 >> 2) & 7);

    auto stageA = [&](int t, int h) {
        const bf16_t* s0 = Ab + (long)(h * 128 + r0) * K + t * 64 + ca0 * 8;
        const bf16_t* s1 = Ab + (long)(h * 128 + r1) * K + t * 64 + ca1 * 8;
        bf16_t* d = lds + ((t & 1) * 2 + h) * 8192;
        __builtin_amdgcn_global_load_lds((const __attribute__((address_space(1))) void*)s0,
            (__attribute__((address_space(3))) void*)(d + c0 * 8), 16, 0, 0);
        __builtin_amdgcn_global_load_lds((const __attribute__((address_space(1))) void*)s1,
            (__attribute__((address_space(3))) void*)(d + c1 * 8), 16, 0, 0);
    };
    auto stageB = [&](int t, int h) {
        const bf16_t* s0 = Bb + (long)(h * 128 + r0) * K + t * 64 + cb0 * 8;
        const bf16_t* s1 = Bb + (long)(h * 128 + r1) * K + t * 64 + cb1 * 8;
        bf16_t* d = lds + 32768 + ((t & 1) * 2 + h) * 8192;
        __builtin_amdgcn_global_load_lds((const __attribute__((address_space(1))) void*)s0,
            (__attribute__((address_space(3))) void*)(d + c0 * 8), 16, 0, 0);
        __builtin_amdgcn_global_load_lds((const __attribute__((address_space(1))) void*)s1,
            (__attribute__((address_space(3))) void*)(d + c1 * 8), 16, 0, 0);
    };
    auto ldA = [&](int t, int mf, int kk) -> bf16x8 {
        const int row = mf * 16 + lrow;
        const int col = (kk * 32 + kgrp * 8) ^ ((row & 7) << 3);
        return *(const bf16x8*)(lds + ((t & 1) * 2 + wm) * 8192 + row * 64 + col);
    };
    auto ldB = [&](int t, int g, int kk) -> bf16x8 {
        const int row = (wn & 1) * 64 + lrow * 4 + g;
        const int col = (kk * 32 + kgrp * 8) ^ (((row >> 2) & 7) << 3);
        return *(const bf16x8*)(lds + 32768 + ((t & 1) * 2 + (wn >> 1)) * 8192 + row * 64 + col);
    };

    f32x4 acc[8][4] = {};
    bf16x8 bfr[4][2];

    // prologue: T0 A+B, T1 B; wait until only T1B (4 loads) in flight
    stageA(0, 0); stageA(0, 1); stageB(0, 0); stageB(0, 1); stageB(1, 0); stageB(1, 1);
    asm volatile("s_waitcnt vmcnt(4)" ::: "memory");
    __builtin_amdgcn_s_barrier();

#pragma unroll
    for (int i = 0; i < 2; ++i) {
#pragma unroll
        for (int p = 0; p < 8; ++p) {
            const int q = p & 3;
            const int t = 2 * i + (p >> 2);
            bf16x8 af[2][2];
            if (q == 0) {
#pragma unroll
                for (int g = 0; g < 4; ++g) { bfr[g][0] = ldB(t, g, 0); bfr[g][1] = ldB(t, g, 1); }
            }
#pragma unroll
            for (int mm = 0; mm < 2; ++mm) { af[mm][0] = ldA(t, 2 * q + mm, 0); af[mm][1] = ldA(t, 2 * q + mm, 1); }

            // stage schedule: p0,p1: T(2i+1)A; p2,p3: T(2i+2)B; p4,p5: T(2i+2)A; p6,p7: T(2i+3)B
            if (p == 0) stageA(2 * i + 1, 0);
            else if (p == 1) stageA(2 * i + 1, 1);
            else if (p == 2) { if (2 * i + 2 < 4) stageB(2 * i + 2, 0); }
            else if (p == 3) { if (2 * i + 2 < 4) stageB(2 * i + 2, 1); }
            else if (p == 4) { if (2 * i + 2 < 4) stageA(2 * i + 2, 0); }
            else if (p == 5) { if (2 * i + 2 < 4) stageA(2 * i + 2, 1); }
            else if (p == 6) { if (2 * i + 3 < 4) stageB(2 * i + 3, 0); }
            else             { if (2 * i + 3 < 4) stageB(2 * i + 3, 1); }

            __builtin_amdgcn_s_barrier();
            asm volatile("s_waitcnt lgkmcnt(0)" ::: "memory");
            __builtin_amdgcn_s_setprio(1);
#pragma unroll
            for (int mm = 0; mm < 2; ++mm)
#pragma unroll
                for (int g = 0; g < 4; ++g)
#pragma unroll
                    for (int kk = 0; kk < 2; ++kk)
                        acc[2 * q + mm][g] = __builtin_amdgcn_mfma_f32_16x16x32_bf16(
                            af[mm][kk], bfr[g][kk], acc[2 * q + mm][g], 0, 0, 0);
            __builtin_amdgcn_s_setprio(0);

            if (p == 3) {
                if (2 * i + 2 < 4) asm volatile("s_waitcnt vmcnt(4)" ::: "memory");
                else               asm volatile("s_waitcnt vmcnt(0)" ::: "memory");
            } else if (p == 7) {
                if (2 * i + 2 < 4) asm volatile("s_waitcnt vmcnt(4)" ::: "memory");
            }
            __builtin_amdgcn_s_barrier();
        }
    }

    // epilogue: lane owns rows (rb + m*16 + j), 4 consecutive cols at cb
    const long rb = (long)mblk * 256 + wm * 128 + kgrp * 4;
    const long cb = (long)nblk * 256 + wn * 64 + lrow * 4;
    if constexpr (EPI == 0) {
        float* C = (float*)Cv + (long)bz * sC;
#pragma unroll
        for (int m = 0; m < 8; ++m)
#pragma unroll
            for (int j = 0; j < 4; ++j) {
                f32x4 v = { acc[m][0][j], acc[m][1][j], acc[m][2][j], acc[m][3][j] };
                __builtin_nontemporal_store(v, (f32x4*)(C + (rb + m * 16 + j) * N + cb));
            }
    } else {
        bf16_t* C = (bf16_t*)Cv;
        f32x4 bv = *(const f32x4*)(bias + (int)(cb & 255));
#pragma unroll
        for (int m = 0; m < 8; ++m)
#pragma unroll
            for (int j = 0; j < 4; ++j) {
                bf16x4 v;
#pragma unroll
                for (int g = 0; g < 4; ++g) v[g] = (bf16_t)(acc[m][g][j] + bv[g]);
                *(bf16x4*)(C + (rb + m * 16 + j) * N + cb) = v;
            }
    }
}

// ---------------------------------------------------------------------------
// B=8, S=1024, IN=768, E=256, L=12
// ---------------------------------------------------------------------------
extern "C" void kernel_launch(void* const* d_in, const int* in_sizes, int n_in,
                              void* d_out, int out_size, void* d_ws, size_t ws_size,
                              hipStream_t stream) {
    const float* input = (const float*)d_in[0];
    const float* fc_w  = (const float*)d_in[1];
    const float* fc_b  = (const float*)d_in[2];
    const float* bi_w  = (const float*)d_in[3];
    const float* bias  = (const float*)d_in[4];

    char* ws = (char*)d_ws;
    bf16_t* inA = (bf16_t*)(ws);             // 8192*768*2
    bf16_t* wfc = (bf16_t*)(ws + 12582912);  // 256*768*2
    bf16_t* wbi = (bf16_t*)(ws + 12976128);  // 3072*256*2
    bf16_t* t   = (bf16_t*)(ws + 14548992);  // 8192*256*2
    bf16_t* bl  = (bf16_t*)(ws + 18743296);  // 8192*3072*2

    cvt_all<<<dim3(3552), dim3(256), 0, stream>>>(input, inA, fc_w, wfc, bi_w, wbi);

    // GEMM1: t = inA @ wfc^T + fc_b   (K=768; 64x64 tile -> 512 blocks)
    gemm_bt<64, 64, 1><<<dim3(128, 4), dim3(256), 0, stream>>>(
        inA, wfc, (void*)t, fc_b, 8192, 256, 768);

    // GEMM2: bl = t @ wbi^T + bias[col&255]  (8-phase 256^2; 32x12 = 384 blocks)
    gemm8p<2, 0, 32, 12><<<dim3(384), dim3(512), 131072, stream>>>(
        t, wbi, (void*)bl, bias, 3072, 0L, 0L, 0L);

    // GEMM3 (batched x8): out_b = bl_b @ t_b^T  (8-phase; 48x4x8 = 1536 blocks)
    gemm8p<0, 1, 48, 4><<<dim3(1536), dim3(512), 131072, stream>>>(
        bl, t, d_out, nullptr, 1024,
        (long)12288 * 256, (long)1024 * 256, (long)12288 * 1024);
}

// Round 6
// 124.975 us; speedup vs baseline: 1.4892x; 1.0876x over previous
//
#include <hip/hip_runtime.h>
#include <hip/hip_bf16.h>

typedef __bf16 bf16_t;
typedef __bf16 bf16x8 __attribute__((ext_vector_type(8)));
typedef __bf16 bf16x4 __attribute__((ext_vector_type(4)));
typedef float f32x4 __attribute__((ext_vector_type(4)));

// ---------------------------------------------------------------------------
// fused fp32 -> bf16 conversion for all three inputs (one dispatch).
// ---------------------------------------------------------------------------
__global__ __launch_bounds__(256)
void cvt_all(const float* __restrict__ in, bf16_t* __restrict__ o_in,
             const float* __restrict__ fw, bf16_t* __restrict__ o_fw,
             const float* __restrict__ bw, bf16_t* __restrict__ o_bw) {
    int i = blockIdx.x * 256 + threadIdx.x;
    const float* s;
    bf16_t* d;
    int k;
    if (i < 786432)      { s = in; d = o_in; k = i; }
    else if (i < 811008) { s = fw; d = o_fw; k = i - 786432; }
    else if (i < 909312) { s = bw; d = o_bw; k = i - 811008; }
    else return;
    float4 a = ((const float4*)s)[k * 2];
    float4 b = ((const float4*)s)[k * 2 + 1];
    bf16x8 v;
    v[0] = (bf16_t)a.x; v[1] = (bf16_t)a.y; v[2] = (bf16_t)a.z; v[3] = (bf16_t)a.w;
    v[4] = (bf16_t)b.x; v[5] = (bf16_t)b.y; v[6] = (bf16_t)b.z; v[7] = (bf16_t)b.w;
    ((bf16x8*)d)[k] = v;
}

// ---------------------------------------------------------------------------
// gemm_bt 64x64 (m97 structure) — GEMM1 only (K=768, N=256).
// ---------------------------------------------------------------------------
template <int BM, int BN, int EPI>
__global__ __launch_bounds__(256)
void gemm_bt(const bf16_t* __restrict__ A, const bf16_t* __restrict__ Bm,
             void* __restrict__ Cv, const float* __restrict__ bias,
             int M, int N, int K) {
    constexpr int MR = BM / 32;
    constexpr int NR = BN / 32;
    typedef float fvec __attribute__((ext_vector_type(NR)));
    typedef bf16_t bvec __attribute__((ext_vector_type(NR)));

    __shared__ bf16_t As[BM * 64];
    __shared__ bf16_t Bs[BN * 64];

    const int tid  = threadIdx.x;
    const int lane = tid & 63;
    const int wave = tid >> 6;
    const int mblk = blockIdx.x, nblk = blockIdx.y;

    const bf16_t* Ab = A + (long)mblk * BM * K;
    const bf16_t* Bb = Bm + (long)nblk * BN * K;

    f32x4 acc[MR][NR] = {};

    const int wrow = (wave >> 1) * (BM / 2);
    const int wcol = (wave & 1) * (BN / 2);
    const int lrow = lane & 15;
    const int kgrp = lane >> 4;

    for (int k0 = 0; k0 < K; k0 += 64) {
#pragma unroll
        for (int it = 0; it < MR; ++it) {
            const int chunk = it * 256 + tid;
            const int row = chunk >> 3, c8 = chunk & 7;
            __builtin_amdgcn_global_load_lds(
                (const __attribute__((address_space(1))) void*)(Ab + (long)row * K + k0 + c8 * 8),
                (__attribute__((address_space(3))) void*)(As + chunk * 8), 16, 0, 0);
        }
#pragma unroll
        for (int it = 0; it < NR; ++it) {
            const int chunk = it * 256 + tid;
            const int row = chunk >> 3, c8 = chunk & 7;
            __builtin_amdgcn_global_load_lds(
                (const __attribute__((address_space(1))) void*)(Bb + (long)row * K + k0 + c8 * 8),
                (__attribute__((address_space(3))) void*)(Bs + chunk * 8), 16, 0, 0);
        }
        __syncthreads();

#pragma unroll
        for (int kk = 0; kk < 64; kk += 32) {
            const int koff = kk + kgrp * 8;
            bf16x8 af[MR], bfr[NR];
#pragma unroll
            for (int m = 0; m < MR; ++m)
                af[m] = *(const bf16x8*)(As + (wrow + m * 16 + lrow) * 64 + koff);
#pragma unroll
            for (int n = 0; n < NR; ++n)
                bfr[n] = *(const bf16x8*)(Bs + (wcol + lrow * NR + n) * 64 + koff);
#pragma unroll
            for (int m = 0; m < MR; ++m)
#pragma unroll
                for (int n = 0; n < NR; ++n)
                    acc[m][n] = __builtin_amdgcn_mfma_f32_16x16x32_bf16(af[m], bfr[n], acc[m][n], 0, 0, 0);
        }
        __syncthreads();
    }

    const long rbase = (long)mblk * BM + wrow + kgrp * 4;
    const long cb0   = (long)nblk * BN + wcol + lrow * NR;
    bf16_t* C = (bf16_t*)Cv;
    const float* bp = bias + cb0;
    fvec bv = *(const fvec*)bp;
#pragma unroll
    for (int m = 0; m < MR; ++m)
#pragma unroll
        for (int j = 0; j < 4; ++j) {
            bvec v;
#pragma unroll
            for (int n = 0; n < NR; ++n) v[n] = (bf16_t)(acc[m][n][j] + bv[n]);
            *(bvec*)(C + (rbase + m * 16 + j) * N + cb0) = v;
        }
}

// ---------------------------------------------------------------------------
// 8-phase 256x256 GEMM, K=256 — GEMM2 only (compute-bound, bf16 out).
// ---------------------------------------------------------------------------
template <int EPI, int XCD, int NMB, int NNB>
__global__ __launch_bounds__(512, 2)
void gemm8p(const bf16_t* __restrict__ A, const bf16_t* __restrict__ Bm,
            void* __restrict__ Cv, const float* __restrict__ bias,
            int N, long sA, long sB, long sC) {
    constexpr int K = 256;
    extern __shared__ bf16_t lds[];

    const int tid  = threadIdx.x;
    const int lane = tid & 63;
    const int wave = tid >> 6;
    const int wm = wave >> 2, wn = wave & 3;
    const int lrow = lane & 15, kgrp = lane >> 4;

    int mblk, nblk, bz;
    {
        int L = blockIdx.x;
        if (XCD) { bz = L & 7; int w = L >> 3; nblk = w % NNB; mblk = w / NNB; }
        else     { bz = 0;     mblk = L % NMB; nblk = L / NMB; }
    }

    const bf16_t* Ab = A + (long)bz * sA + (long)mblk * 256 * K;
    const bf16_t* Bb = Bm + (long)bz * sB + (long)nblk * 256 * K;

    const int c0 = tid, c1 = 512 + tid;
    const int r0 = c0 >> 3, r1 = c1 >> 3;
    const int ca0 = (c0 & 7) ^ (r0 & 7),        ca1 = (c1 & 7) ^ (r1 & 7);
    const int cb0 = (c0 & 7) ^ ((r0 >> 2) & 7), cb1 = (c1 & 7) ^ ((r1 >> 2) & 7);

    auto stageA = [&](int t, int h) {
        const bf16_t* s0 = Ab + (long)(h * 128 + r0) * K + t * 64 + ca0 * 8;
        const bf16_t* s1 = Ab + (long)(h * 128 + r1) * K + t * 64 + ca1 * 8;
        bf16_t* d = lds + ((t & 1) * 2 + h) * 8192;
        __builtin_amdgcn_global_load_lds((const __attribute__((address_space(1))) void*)s0,
            (__attribute__((address_space(3))) void*)(d + c0 * 8), 16, 0, 0);
        __builtin_amdgcn_global_load_lds((const __attribute__((address_space(1))) void*)s1,
            (__attribute__((address_space(3))) void*)(d + c1 * 8), 16, 0, 0);
    };
    auto stageB = [&](int t, int h) {
        const bf16_t* s0 = Bb + (long)(h * 128 + r0) * K + t * 64 + cb0 * 8;
        const bf16_t* s1 = Bb + (long)(h * 128 + r1) * K + t * 64 + cb1 * 8;
        bf16_t* d = lds + 32768 + ((t & 1) * 2 + h) * 8192;
        __builtin_amdgcn_global_load_lds((const __attribute__((address_space(1))) void*)s0,
            (__attribute__((address_space(3))) void*)(d + c0 * 8), 16, 0, 0);
        __builtin_amdgcn_global_load_lds((const __attribute__((address_space(1))) void*)s1,
            (__attribute__((address_space(3))) void*)(d + c1 * 8), 16, 0, 0);
    };
    auto ldA = [&](int t, int mf, int kk) -> bf16x8 {
        const int row = mf * 16 + lrow;
        const int col = (kk * 32 + kgrp * 8) ^ ((row & 7) << 3);
        return *(const bf16x8*)(lds + ((t & 1) * 2 + wm) * 8192 + row * 64 + col);
    };
    auto ldB = [&](int t, int g, int kk) -> bf16x8 {
        const int row = (wn & 1) * 64 + lrow * 4 + g;
        const int col = (kk * 32 + kgrp * 8) ^ (((row >> 2) & 7) << 3);
        return *(const bf16x8*)(lds + 32768 + ((t & 1) * 2 + (wn >> 1)) * 8192 + row * 64 + col);
    };

    f32x4 acc[8][4] = {};
    bf16x8 bfr[4][2];

    stageA(0, 0); stageA(0, 1); stageB(0, 0); stageB(0, 1); stageB(1, 0); stageB(1, 1);
    asm volatile("s_waitcnt vmcnt(4)" ::: "memory");
    __builtin_amdgcn_s_barrier();

#pragma unroll
    for (int i = 0; i < 2; ++i) {
#pragma unroll
        for (int p = 0; p < 8; ++p) {
            const int q = p & 3;
            const int t = 2 * i + (p >> 2);
            bf16x8 af[2][2];
            if (q == 0) {
#pragma unroll
                for (int g = 0; g < 4; ++g) { bfr[g][0] = ldB(t, g, 0); bfr[g][1] = ldB(t, g, 1); }
            }
#pragma unroll
            for (int mm = 0; mm < 2; ++mm) { af[mm][0] = ldA(t, 2 * q + mm, 0); af[mm][1] = ldA(t, 2 * q + mm, 1); }

            if (p == 0) stageA(2 * i + 1, 0);
            else if (p == 1) stageA(2 * i + 1, 1);
            else if (p == 2) { if (2 * i + 2 < 4) stageB(2 * i + 2, 0); }
            else if (p == 3) { if (2 * i + 2 < 4) stageB(2 * i + 2, 1); }
            else if (p == 4) { if (2 * i + 2 < 4) stageA(2 * i + 2, 0); }
            else if (p == 5) { if (2 * i + 2 < 4) stageA(2 * i + 2, 1); }
            else if (p == 6) { if (2 * i + 3 < 4) stageB(2 * i + 3, 0); }
            else             { if (2 * i + 3 < 4) stageB(2 * i + 3, 1); }

            __builtin_amdgcn_s_barrier();
            asm volatile("s_waitcnt lgkmcnt(0)" ::: "memory");
            __builtin_amdgcn_s_setprio(1);
#pragma unroll
            for (int mm = 0; mm < 2; ++mm)
#pragma unroll
                for (int g = 0; g < 4; ++g)
#pragma unroll
                    for (int kk = 0; kk < 2; ++kk)
                        acc[2 * q + mm][g] = __builtin_amdgcn_mfma_f32_16x16x32_bf16(
                            af[mm][kk], bfr[g][kk], acc[2 * q + mm][g], 0, 0, 0);
            __builtin_amdgcn_s_setprio(0);

            if (p == 3) {
                if (2 * i + 2 < 4) asm volatile("s_waitcnt vmcnt(4)" ::: "memory");
                else               asm volatile("s_waitcnt vmcnt(0)" ::: "memory");
            } else if (p == 7) {
                if (2 * i + 2 < 4) asm volatile("s_waitcnt vmcnt(4)" ::: "memory");
            }
            __builtin_amdgcn_s_barrier();
        }
    }

    const long rb = (long)mblk * 256 + wm * 128 + kgrp * 4;
    const long cb = (long)nblk * 256 + wn * 64 + lrow * 4;
    if constexpr (EPI == 0) {
        float* C = (float*)Cv + (long)bz * sC;
#pragma unroll
        for (int m = 0; m < 8; ++m)
#pragma unroll
            for (int j = 0; j < 4; ++j) {
                f32x4 v = { acc[m][0][j], acc[m][1][j], acc[m][2][j], acc[m][3][j] };
                __builtin_nontemporal_store(v, (f32x4*)(C + (rb + m * 16 + j) * N + cb));
            }
    } else {
        bf16_t* C = (bf16_t*)Cv;
        f32x4 bv = *(const f32x4*)(bias + (int)(cb & 255));
#pragma unroll
        for (int m = 0; m < 8; ++m)
#pragma unroll
            for (int j = 0; j < 4; ++j) {
                bf16x4 v;
#pragma unroll
                for (int g = 0; g < 4; ++g) v[g] = (bf16_t)(acc[m][g][j] + bv[g]);
                *(bf16x4*)(C + (rb + m * 16 + j) * N + cb) = v;
            }
    }
}

// ---------------------------------------------------------------------------
// GEMM3: out_b = bl_b[12288,256] @ t_b[1024,256]^T, fp32 NT out. WRITE-BOUND.
// 192x128 tile, BK=64 double-buffered, 256 threads (4 waves 2x2, wave tile
// 96x64), LDS = 80 KB -> 2 blocks/CU co-resident (acc 96 VGPR, ~200 total,
// 2 waves/SIMD) so one block's K-loop overlaps the other's store drain.
// T3-minimum 2-phase: stage(t+1) -> ds_read(t) -> 48 MFMA -> __syncthreads
// (drains vmcnt+lgkm; stage targets the buffer whose reads completed at the
// PREVIOUS barrier -> race-free). Swizzle keys as gemm8p (A row&7, B row>>2&7).
// ---------------------------------------------------------------------------
template <int NNB>
__global__ __launch_bounds__(256, 2)
void gemm3k(const bf16_t* __restrict__ A, const bf16_t* __restrict__ Bm,
            float* __restrict__ C, long sA, long sB, long sC) {
    constexpr int K = 256, BM = 192, BN = 128;
    extern __shared__ bf16_t lds[];   // A: buf*12288 ; B: 24576 + buf*8192

    const int tid  = threadIdx.x;
    const int lane = tid & 63;
    const int wave = tid >> 6;
    const int wm = wave >> 1, wn = wave & 1;
    const int lrow = lane & 15, kgrp = lane >> 4;

    const int L = blockIdx.x;
    const int bz = L & 7;
    const int w = L >> 3;
    const int nblk = w & (NNB - 1), mblk = w / NNB;

    const bf16_t* Ab = A + (long)bz * sA + (long)mblk * BM * K;
    const bf16_t* Bb = Bm + (long)bz * sB + (long)nblk * BN * K;

    auto stage = [&](int t) {
        const int buf = t & 1;
#pragma unroll
        for (int it = 0; it < 6; ++it) {          // A: 192x64 = 1536 chunks
            const int c = it * 256 + tid, row = c >> 3;
            const int sa = (c & 7) ^ (row & 7);
            __builtin_amdgcn_global_load_lds(
                (const __attribute__((address_space(1))) void*)(Ab + (long)row * K + t * 64 + sa * 8),
                (__attribute__((address_space(3))) void*)(lds + buf * 12288 + c * 8), 16, 0, 0);
        }
#pragma unroll
        for (int it = 0; it < 4; ++it) {          // B: 128x64 = 1024 chunks
            const int c = it * 256 + tid, row = c >> 3;
            const int sb = (c & 7) ^ ((row >> 2) & 7);
            __builtin_amdgcn_global_load_lds(
                (const __attribute__((address_space(1))) void*)(Bb + (long)row * K + t * 64 + sb * 8),
                (__attribute__((address_space(3))) void*)(lds + 24576 + buf * 8192 + c * 8), 16, 0, 0);
        }
    };

    f32x4 acc[6][4] = {};

    stage(0);
    __syncthreads();

#pragma unroll
    for (int t = 0; t < 4; ++t) {
        if (t < 3) stage(t + 1);
        const int buf = t & 1;
        bf16x8 af[6][2], bfr[4][2];
#pragma unroll
        for (int m = 0; m < 6; ++m) {
            const int r = wm * 96 + m * 16 + lrow;
#pragma unroll
            for (int kk = 0; kk < 2; ++kk)
                af[m][kk] = *(const bf16x8*)(lds + buf * 12288 + r * 64 +
                                             ((kk * 32 + kgrp * 8) ^ ((r & 7) << 3)));
        }
#pragma unroll
        for (int g = 0; g < 4; ++g) {
            const int r = wn * 64 + lrow * 4 + g;
#pragma unroll
            for (int kk = 0; kk < 2; ++kk)
                bfr[g][kk] = *(const bf16x8*)(lds + 24576 + buf * 8192 + r * 64 +
                                              ((kk * 32 + kgrp * 8) ^ (((r >> 2) & 7) << 3)));
        }
        __builtin_amdgcn_s_setprio(1);
#pragma unroll
        for (int m = 0; m < 6; ++m)
#pragma unroll
            for (int g = 0; g < 4; ++g)
#pragma unroll
                for (int kk = 0; kk < 2; ++kk)
                    acc[m][g] = __builtin_amdgcn_mfma_f32_16x16x32_bf16(
                        af[m][kk], bfr[g][kk], acc[m][g], 0, 0, 0);
        __builtin_amdgcn_s_setprio(0);
        __syncthreads();
    }

    float* Cb = C + (long)bz * sC;
    const long rb = (long)mblk * BM + wm * 96 + kgrp * 4;
    const long cb = (long)nblk * BN + wn * 64 + lrow * 4;
#pragma unroll
    for (int m = 0; m < 6; ++m)
#pragma unroll
        for (int j = 0; j < 4; ++j) {
            f32x4 v = { acc[m][0][j], acc[m][1][j], acc[m][2][j], acc[m][3][j] };
            __builtin_nontemporal_store(v, (f32x4*)(Cb + (rb + m * 16 + j) * 1024 + cb));
        }
}

// ---------------------------------------------------------------------------
// B=8, S=1024, IN=768, E=256, L=12
// ---------------------------------------------------------------------------
extern "C" void kernel_launch(void* const* d_in, const int* in_sizes, int n_in,
                              void* d_out, int out_size, void* d_ws, size_t ws_size,
                              hipStream_t stream) {
    const float* input = (const float*)d_in[0];
    const float* fc_w  = (const float*)d_in[1];
    const float* fc_b  = (const float*)d_in[2];
    const float* bi_w  = (const float*)d_in[3];
    const float* bias  = (const float*)d_in[4];

    char* ws = (char*)d_ws;
    bf16_t* inA = (bf16_t*)(ws);             // 8192*768*2
    bf16_t* wfc = (bf16_t*)(ws + 12582912);  // 256*768*2
    bf16_t* wbi = (bf16_t*)(ws + 12976128);  // 3072*256*2
    bf16_t* t   = (bf16_t*)(ws + 14548992);  // 8192*256*2
    bf16_t* bl  = (bf16_t*)(ws + 18743296);  // 8192*3072*2

    cvt_all<<<dim3(3552), dim3(256), 0, stream>>>(input, inA, fc_w, wfc, bi_w, wbi);

    // GEMM1: t = inA @ wfc^T + fc_b   (K=768; 64x64 tile -> 512 blocks)
    gemm_bt<64, 64, 1><<<dim3(128, 4), dim3(256), 0, stream>>>(
        inA, wfc, (void*)t, fc_b, 8192, 256, 768);

    // GEMM2: bl = t @ wbi^T + bias[col&255]  (8-phase 256^2; 384 blocks)
    gemm8p<2, 0, 32, 12><<<dim3(384), dim3(512), 131072, stream>>>(
        t, wbi, (void*)bl, bias, 3072, 0L, 0L, 0L);

    // GEMM3 (batched x8): out_b = bl_b @ t_b^T
    // 192x128 tile: 64 mblk x 8 nblk x 8 batch = 4096 blocks, 2/CU, NT stores
    gemm3k<8><<<dim3(4096), dim3(256), 81920, stream>>>(
        bl, t, (float*)d_out,
        (long)12288 * 256, (long)1024 * 256, (long)12288 * 1024);
}